// Round 5
// baseline (940.553 us; speedup 1.0000x reference)
//
#include <hip/hip_runtime.h>
#include <hip/hip_bf16.h>
#include <math.h>

// Problem constants
#define BB 4
#define MM 20
#define LL 200
#define INC 2048
#define C1 512
#define C2 256
#define CDIM 300
#define DC1 512
#define DC2 256
#define SDIM 1024
#define BM 80           // B*M
#define L2 100          // L/2
#define L4 50           // L/4

typedef unsigned short u16;
typedef __attribute__((ext_vector_type(8))) short bf16x8;
typedef __attribute__((ext_vector_type(4))) float f32x4;

__device__ __forceinline__ u16 f2bf_rne(float f) {
  unsigned u = __float_as_uint(f);
  unsigned r = u + 0x7FFFu + ((u >> 16) & 1u);
  return (u16)(r >> 16);
}
__device__ __forceinline__ float bf2f(u16 v) {
  return __uint_as_float(((unsigned)v) << 16);
}

// ---------------- generic fp32 -> bf16 cast ----------------
__global__ void k_cast_bf16(const float* __restrict__ in, u16* __restrict__ out, int n8) {
  int idx = blockIdx.x * 256 + threadIdx.x;
  if (idx >= n8) return;
  const float4* p = (const float4*)in + (long long)idx * 2;
  float4 a = p[0], b = p[1];
  uint4 o;
  o.x = (unsigned)f2bf_rne(a.x) | ((unsigned)f2bf_rne(a.y) << 16);
  o.y = (unsigned)f2bf_rne(a.z) | ((unsigned)f2bf_rne(a.w) << 16);
  o.z = (unsigned)f2bf_rne(b.x) | ((unsigned)f2bf_rne(b.y) << 16);
  o.w = (unsigned)f2bf_rne(b.z) | ((unsigned)f2bf_rne(b.w) << 16);
  *(uint4*)(out + (long long)idx * 8) = o;
}

// conv weight [co][ci][t] -> [co][t][ci]  (= B[N][K], K = 5*Cin)
__global__ void k_conv_w_t(const float* __restrict__ in, u16* __restrict__ out,
                           int Cout, int Cin, int Kk) {
  int idx = blockIdx.x * 256 + threadIdx.x;
  int total = Cout * Cin * Kk;
  if (idx >= total) return;
  int ci = idx % Cin;
  int t  = (idx / Cin) % Kk;
  int co = idx / (Cin * Kk);
  out[idx] = f2bf_rne(in[(co * Cin + ci) * Kk + t]);
}

// deconv weight [ci][co][4] -> per-parity conv weights [z][co][tt][ci], t = 3 - z - 2*tt
__global__ void k_deconv_w_par(const float* __restrict__ in, u16* __restrict__ out,
                               int Cin, int Cout) {
  int idx = blockIdx.x * 256 + threadIdx.x;
  int total = Cin * Cout * 4;
  if (idx >= total) return;
  int ci = idx % Cin;
  int tt = (idx / Cin) & 1;
  int co = (idx / (2 * Cin)) % Cout;
  int zz = idx / (2 * Cin * Cout);
  out[idx] = f2bf_rne(in[(ci * Cout + co) * 4 + 3 - zz - 2 * tt]);
}

// ---------------- small precompute: q[z][b][c], v[z][b][c] ----------------
__global__ __launch_bounds__(256) void k_prep_small(
    const float* __restrict__ concept1, const float* __restrict__ concept2,
    const float* __restrict__ w_ca1, const float* __restrict__ w_sim1,
    const float* __restrict__ w_sim2, const float* __restrict__ w_mlp,
    float* __restrict__ qv) {
  int cz = blockIdx.x >> 2;
  int b  = blockIdx.x & 3;
  const float* con = cz ? concept2 : concept1;
  __shared__ float cvec[CDIM];
  __shared__ float chat[SDIM];
  int tid = threadIdx.x;
  for (int j = tid; j < CDIM; j += 256) cvec[j] = con[b * CDIM + j];
  __syncthreads();
  float accq = 0.f;
  for (int j = 0; j < CDIM; ++j) accq += cvec[j] * w_ca1[tid * CDIM + j];
  qv[(cz * 4 + b) * 256 + tid] = accq;
  for (int i = 0; i < 4; ++i) {
    int s = tid + i * 256;
    float a2 = 0.f;
    for (int j = 0; j < CDIM; ++j) a2 += cvec[j] * w_sim2[s * CDIM + j];
    chat[s] = a2 * w_mlp[s];
  }
  __syncthreads();
  float v = 0.f;
  for (int s = 0; s < SDIM; ++s) v += w_sim1[s * 256 + tid] * chat[s];
  qv[2048 + (cz * 4 + b) * 256 + tid] = v;
}

// ---------------- unified bf16-MFMA NT GEMM ----------------
// C = A * B^T with im2col row mapping: A row r -> (n=r/lr, l=r%lr); k-index
// (tap,ci) reads A[(n*lr + l+tap-pad)*cin + ci], zero outside. Plain: lr=M,cin=K.
// EP_PLAIN: fp32 store to C + z*sC, K-range [z*ksub, z*ksub+Kx) (split-K when z>1).
// EP_ILV:   z = deconv parity (pad = 1-z, B at z*sB); bf16 store with bias at
//           interleaved row n*2*lr + 2*l + z.
// AF32: A is fp32 (truncate to bf16 in staging); else A is bf16.
#define EP_PLAIN 0
#define EP_ILV   1
#define LDK 68   // LDS row stride u16: 34 words -> reads conflict-free, writes 4-way

template <int EP, int AF32>
__global__ __launch_bounds__(256) void k_mfma_gemm(
    const void* __restrict__ Ain, const u16* __restrict__ Bw,
    void* __restrict__ Co, const float* __restrict__ bias,
    int M, int N, int Kx, int Ktot, int lr, int cin, int pad_,
    int gx, int gy, long long sB, long long sC, int ksub) {
  __shared__ __align__(16) u16 As[128 * LDK];
  __shared__ __align__(16) u16 Bs[128 * LDK];
  int id = blockIdx.x;
  int x = (id >> 3) % gx;
  int y = (id & 7) + 8 * ((id >> 3) / gx);
  if (y >= gy) return;
  int z = blockIdx.z;
  int pad = (EP == EP_ILV) ? (1 - z) : pad_;
  int kbeg = ksub * z;
  int row0 = y * 128, col0 = x * 128;
  int tid = threadIdx.x;
  int w = tid >> 6, ln = tid & 63;
  const u16* Bz = Bw + (long long)z * sB + kbeg;

  // staging map: rows i*32 + (tid>>3), k-offset (tid&7)*8
  int sub = (tid & 7) * 8;
  int rrb = tid >> 3;
  int an[4], al[4];
  #pragma unroll
  for (int i = 0; i < 4; ++i) {
    int r = row0 + i * 32 + rrb;
    if (r > M - 1) r = M - 1;
    an[i] = r / lr;
    al[i] = r - an[i] * lr;
  }
  f32x4 acc[4][4];
  #pragma unroll
  for (int i = 0; i < 4; ++i)
    #pragma unroll
    for (int j = 0; j < 4; ++j) acc[i][j] = (f32x4){0.f, 0.f, 0.f, 0.f};

  int wr = (w >> 1) * 64, wc = (w & 1) * 64;

  int tap = kbeg / cin, ci0 = kbeg - (kbeg / cin) * cin;
  for (int kk = 0; kk < Kx; kk += 64) {
    #pragma unroll
    for (int i = 0; i < 4; ++i) {
      int j = al[i] + tap - pad;
      uint4 pk = make_uint4(0u, 0u, 0u, 0u);
      if (j >= 0 && j < lr) {
        long long base = (long long)(an[i] * lr + j) * cin + ci0 + sub;
        if (AF32) {
          const float* Af = (const float*)Ain + base;
          float4 f0 = *(const float4*)Af;
          float4 f1 = *(const float4*)(Af + 4);
          pk.x = (__float_as_uint(f0.x) >> 16) | (__float_as_uint(f0.y) & 0xFFFF0000u);
          pk.y = (__float_as_uint(f0.z) >> 16) | (__float_as_uint(f0.w) & 0xFFFF0000u);
          pk.z = (__float_as_uint(f1.x) >> 16) | (__float_as_uint(f1.y) & 0xFFFF0000u);
          pk.w = (__float_as_uint(f1.z) >> 16) | (__float_as_uint(f1.w) & 0xFFFF0000u);
        } else {
          pk = *(const uint4*)((const u16*)Ain + base);
        }
      }
      *(uint4*)&As[(i * 32 + rrb) * LDK + sub] = pk;
    }
    #pragma unroll
    for (int i = 0; i < 4; ++i) {
      int nr = col0 + i * 32 + rrb;
      *(uint4*)&Bs[(i * 32 + rrb) * LDK + sub] =
          *(const uint4*)&Bz[(long long)nr * Ktot + kk + sub];
    }
    __syncthreads();
    #pragma unroll
    for (int ks = 0; ks < 2; ++ks) {
      bf16x8 af[4], bf[4];
      int koff = ks * 32 + (ln >> 4) * 8;
      int arow = wr + (ln & 15);
      int brow = wc + (ln & 15);
      #pragma unroll
      for (int mi = 0; mi < 4; ++mi)
        af[mi] = *(const bf16x8*)&As[(arow + mi * 16) * LDK + koff];
      #pragma unroll
      for (int ni = 0; ni < 4; ++ni)
        bf[ni] = *(const bf16x8*)&Bs[(brow + ni * 16) * LDK + koff];
      #pragma unroll
      for (int mi = 0; mi < 4; ++mi)
        #pragma unroll
        for (int ni = 0; ni < 4; ++ni)
          acc[mi][ni] = __builtin_amdgcn_mfma_f32_16x16x32_bf16(
              af[mi], bf[ni], acc[mi][ni], 0, 0, 0);
    }
    __syncthreads();
    ci0 += 64;
    if (ci0 >= cin) { ci0 = 0; ++tap; }
  }

  // epilogue: C/D layout col = lane&15, row = (lane>>4)*4 + reg
  if (EP == EP_PLAIN) {
    float* Cz = (float*)Co + (long long)z * sC;
    #pragma unroll
    for (int mi = 0; mi < 4; ++mi) {
      int gbase = row0 + wr + mi * 16 + (ln >> 4) * 4;
      #pragma unroll
      for (int r = 0; r < 4; ++r) {
        int grow = gbase + r;
        if (grow < M) {
          #pragma unroll
          for (int ni = 0; ni < 4; ++ni) {
            int col = col0 + wc + ni * 16 + (ln & 15);
            Cz[(long long)grow * N + col] = acc[mi][ni][r];
          }
        }
      }
    }
  } else {
    u16* Cz = (u16*)Co;
    #pragma unroll
    for (int mi = 0; mi < 4; ++mi) {
      int gbase = row0 + wr + mi * 16 + (ln >> 4) * 4;
      #pragma unroll
      for (int r = 0; r < 4; ++r) {
        int grow = gbase + r;
        if (grow < M) {
          int n = grow / lr, jj = grow - n * lr;
          long long orow = (long long)n * 2 * lr + 2 * jj + z;
          #pragma unroll
          for (int ni = 0; ni < 4; ++ni) {
            int col = col0 + wc + ni * 16 + (ln & 15);
            Cz[orow * N + col] = f2bf_rne(acc[mi][ni][r] + bias[col]);
          }
        }
      }
    }
  }
}

// ---------------- split-sum + maxpool2 + bias -> bf16 ----------------
// S: [nsplit][2*Mh][N] fp32 partials; out: [Mh][N] bf16
__global__ void k_pool2(const float* __restrict__ S, const float* __restrict__ bias,
                        u16* __restrict__ outp, int Mh, int N4, long long sz, int nsplit) {
  int idx = blockIdx.x * 256 + threadIdx.x;
  if (idx >= Mh * N4) return;
  int c4 = idx % N4;
  int ro = idx / N4;
  int N = N4 * 4, c = c4 * 4;
  const float* p = S + (long long)(2 * ro) * N + c;
  float4 a = *(const float4*)p;
  float4 b = *(const float4*)(p + N);
  for (int zz = 1; zz < nsplit; ++zz) {
    const float* q = p + zz * sz;
    float4 a2 = *(const float4*)q;
    float4 b2 = *(const float4*)(q + N);
    a.x += a2.x; a.y += a2.y; a.z += a2.z; a.w += a2.w;
    b.x += b2.x; b.y += b2.y; b.z += b2.z; b.w += b2.w;
  }
  float4 bi = *(const float4*)(bias + c);
  ushort4 o;
  o.x = f2bf_rne(fmaxf(a.x, b.x) + bi.x);
  o.y = f2bf_rne(fmaxf(a.y, b.y) + bi.y);
  o.z = f2bf_rne(fmaxf(a.z, b.z) + bi.z);
  o.w = f2bf_rne(fmaxf(a.w, b.w) + bi.w);
  *(ushort4*)(outp + (long long)ro * N + c) = o;
}

// ---------------- attention: wave-parallel scores + softmax + weighted sum ----------------
__global__ __launch_bounds__(256) void k_attention(
    const float* __restrict__ kproj, const u16* __restrict__ t2b,
    const float* __restrict__ qv, const float* __restrict__ w_ca3,
    const int* __restrict__ seg_len, u16* __restrict__ rb) {
  int bm = blockIdx.x % BM;
  int cz = blockIdx.x / BM;
  int b = bm / MM;
  int tid = threadIdx.x, w = tid >> 6, ln = tid & 63;
  __shared__ float sq[256], sw[256], sa[L4 + 14];
  sq[tid] = qv[(cz * 4 + b) * 256 + tid];
  sw[tid] = w_ca3[tid];
  __syncthreads();
  int kmax = (seg_len[bm] + 3) >> 2;
  for (int k = w; k < L4; k += 4) {
    float val = 0.f;
    #pragma unroll
    for (int i = 0; i < 4; ++i) {
      int c = ln + 64 * i;
      val += tanhf(sq[c] + kproj[(bm * L4 + k) * 256 + c]) * sw[c];
    }
    for (int off = 32; off > 0; off >>= 1) val += __shfl_down(val, off, 64);
    if (ln == 0) sa[k] = (k < kmax) ? val : -1e15f;
  }
  __syncthreads();
  if (w == 0) {
    float sv = (ln < L4) ? sa[ln] : -3e38f;
    float mx = sv;
    for (int off = 32; off > 0; off >>= 1) mx = fmaxf(mx, __shfl_down(mx, off, 64));
    mx = __shfl(mx, 0, 64);
    float e = (ln < L4) ? expf(sv - mx) : 0.f;
    float s = e;
    for (int off = 32; off > 0; off >>= 1) s += __shfl_down(s, off, 64);
    s = __shfl(s, 0, 64);
    if (ln < L4) sa[ln] = e / s;
  }
  __syncthreads();
  float r = 0.f;
  for (int k = 0; k < L4; ++k) r += sa[k] * bf2f(t2b[(bm * L4 + k) * 256 + tid]);
  rb[(cz * BM + bm) * 256 + tid] = f2bf_rne(r);
}

// ---------------- build cat matrix [4000][768] bf16 ----------------
__global__ void k_build_cat(const u16* __restrict__ t2b, const u16* __restrict__ rb,
                            u16* __restrict__ catm, int total) {
  int idx = blockIdx.x * 256 + threadIdx.x;
  if (idx >= total) return;
  int ci = idx % 768;
  int row = idx / 768;        // bm*50 + li
  int bm = row / L4;
  u16 v;
  if (ci < 256)      v = t2b[row * 256 + ci];
  else if (ci < 512) v = rb[bm * 256 + (ci - 256)];
  else               v = rb[(BM + bm) * 256 + (ci - 512)];
  catm[idx] = v;
}

// ---------------- final projection + sigmoid (reads bf16 d2) ----------------
__global__ __launch_bounds__(256) void k_final(
    const u16* __restrict__ d2b, const float* __restrict__ qv,
    const float* __restrict__ b_mlp, float* __restrict__ out) {
  int row = blockIdx.x;          // n*200 + lo
  int n = row / LL, lo = row % LL;
  int b = n / MM, m = n % MM;
  int tid = threadIdx.x;
  float v = bf2f(d2b[(long long)row * 256 + tid]);
  float p1 = v * qv[2048 + (0 * 4 + b) * 256 + tid];
  float p2 = v * qv[2048 + (1 * 4 + b) * 256 + tid];
  for (int off = 32; off > 0; off >>= 1) {
    p1 += __shfl_down(p1, off, 64);
    p2 += __shfl_down(p2, off, 64);
  }
  __shared__ float s1[4], s2[4];
  if ((tid & 63) == 0) { s1[tid >> 6] = p1; s2[tid >> 6] = p2; }
  __syncthreads();
  if (tid == 0) {
    float bmlp = b_mlp[0];
    float a1 = s1[0] + s1[1] + s1[2] + s1[3] + bmlp;
    float a2 = s2[0] + s2[1] + s2[2] + s2[3] + bmlp;
    int t_idx = m * LL + lo;
    out[b * 4000 + t_idx]         = 1.f / (1.f + expf(-a1));
    out[16000 + b * 4000 + t_idx] = 1.f / (1.f + expf(-a2));
  }
}

// ---------------- host ----------------
extern "C" void kernel_launch(void* const* d_in, const int* in_sizes, int n_in,
                              void* d_out, int out_size, void* d_ws, size_t ws_size,
                              hipStream_t stream) {
  const float* batch    = (const float*)d_in[0];
  const int*   seg_len  = (const int*)d_in[1];
  const float* concept1 = (const float*)d_in[2];
  const float* concept2 = (const float*)d_in[3];
  const float* w_conv1  = (const float*)d_in[4];
  const float* b_conv1  = (const float*)d_in[5];
  const float* w_conv2  = (const float*)d_in[6];
  const float* b_conv2  = (const float*)d_in[7];
  const float* w_ca1    = (const float*)d_in[8];
  const float* w_ca2    = (const float*)d_in[9];
  const float* w_ca3    = (const float*)d_in[10];
  const float* w_dc1    = (const float*)d_in[11];
  const float* b_dc1    = (const float*)d_in[12];
  const float* w_dc2    = (const float*)d_in[13];
  const float* b_dc2    = (const float*)d_in[14];
  const float* w_sim1   = (const float*)d_in[15];
  const float* w_sim2   = (const float*)d_in[16];
  const float* w_mlp    = (const float*)d_in[17];
  const float* b_mlp    = (const float*)d_in[18];
  float* out = (float*)d_out;

  float* ws = (float*)d_ws;
  // workspace layout (float units) — total 24,023,040 f = 96.1 MB
  const long long off_qv    = 0;          //      4,096
  const long long off_kproj = 4096;       //  1,024,000
  const long long off_rb    = 1028096;    //     20,480 (rb bf16: 40,960 u16)
  const long long off_t1    = 1048576;    //  2,048,000 (t1b bf16)
  const long long off_t2    = 3096576;    //    512,000 (t2b bf16)
  const long long off_w1b   = 3608576;    //  2,621,440 (u16 x2)
  const long long off_w2b   = 6230016;    //    327,680
  const long long off_wd1p  = 6557696;    //    786,432
  const long long off_wd2p  = 7344128;    //    262,144
  const long long off_wca2b = 7606272;    //     32,768
  const long long off_BIG   = 7639040;    // 16,384,000 (Csplit -> Csplit2 -> cat/d1/d2)

  u16* rb    = (u16*)(ws + off_rb);
  u16* t1b   = (u16*)(ws + off_t1);
  u16* t2b   = (u16*)(ws + off_t2);
  u16* w1b   = (u16*)(ws + off_w1b);
  u16* w2b   = (u16*)(ws + off_w2b);
  u16* wd1p  = (u16*)(ws + off_wd1p);
  u16* wd2p  = (u16*)(ws + off_wd2p);
  u16* wca2b = (u16*)(ws + off_wca2b);
  float* Csplit  = ws + off_BIG;                 // [2][16000][512] fp32
  float* Csplit2 = ws + off_BIG;                 // [4][8000][256] fp32 (after pool1)
  u16* catm = (u16*)(ws + off_BIG);              // [4000][768] bf16 (after pool2)
  u16* d1b  = (u16*)(ws + off_BIG + 1536000);    // [80][100][512] bf16
  u16* d2b  = (u16*)(ws + off_BIG + 3584000);    // [16000][256] bf16

  // --- weight prep ---
  k_conv_w_t<<<dim3(20480), 256, 0, stream>>>(w_conv1, w1b, C1, INC, 5);
  k_conv_w_t<<<dim3(2560), 256, 0, stream>>>(w_conv2, w2b, C2, C1, 5);
  k_deconv_w_par<<<dim3(6144), 256, 0, stream>>>(w_dc1, wd1p, 3 * C2, DC1);
  k_deconv_w_par<<<dim3(2048), 256, 0, stream>>>(w_dc2, wd2p, DC1, DC2);
  k_cast_bf16<<<dim3(32), 256, 0, stream>>>(w_ca2, wca2b, 8192);
  k_prep_small<<<dim3(8), 256, 0, stream>>>(concept1, concept2, w_ca1, w_sim1, w_sim2,
                                            w_mlp, ws + off_qv);

  // --- conv1, split-K x2 (A fp32): Csplit[2][16000][512]; pool+bias -> t1b
  k_mfma_gemm<EP_PLAIN, 1><<<dim3(512, 1, 2), 256, 0, stream>>>(
      batch, w1b, Csplit, nullptr, 16000, 512, 5120, 10240, 200, 2048, 2,
      4, 125, 0, 8192000LL, 5120);
  k_pool2<<<dim3(4000), 256, 0, stream>>>(Csplit, b_conv1, t1b, 8000, 128,
                                          8192000LL, 2);

  // --- conv2, split-K x4: Csplit2[4][8000][256]; pool+bias -> t2b
  k_mfma_gemm<EP_PLAIN, 0><<<dim3(128, 1, 4), 256, 0, stream>>>(
      t1b, w2b, Csplit2, nullptr, 8000, 256, 640, 2560, 100, 512, 2,
      2, 63, 0, 2048000LL, 640);
  k_pool2<<<dim3(1000), 256, 0, stream>>>(Csplit2, b_conv2, t2b, 4000, 64,
                                          2048000LL, 4);

  // --- kproj = t2 @ w_ca2^T : [4000][256] fp32
  k_mfma_gemm<EP_PLAIN, 0><<<dim3(64), 256, 0, stream>>>(
      t2b, wca2b, ws + off_kproj, nullptr, 4000, 256, 256, 256, 4000, 256, 0,
      2, 32, 0, 0, 0);

  // --- attention (2 concepts x 80 rows) -> rb bf16
  k_attention<<<dim3(160), 256, 0, stream>>>(ws + off_kproj, t2b, ws + off_qv,
                                             w_ca3, seg_len, rb);

  // --- cat [4000][768] bf16 (Csplit2 dead)
  k_build_cat<<<dim3(12000), 256, 0, stream>>>(t2b, rb, catm, 4000 * 768);

  // --- deconv1 as 2 parity convs (z) + fused bias -> d1b bf16 [80][100][512]
  k_mfma_gemm<EP_ILV, 0><<<dim3(128, 1, 2), 256, 0, stream>>>(
      catm, wd1p, d1b, b_dc1, 4000, 512, 1536, 1536, 50, 768, 0,
      4, 32, 786432LL, 0, 0);

  // --- deconv2 as 2 parity convs + fused bias -> d2b bf16 [16000][256]
  k_mfma_gemm<EP_ILV, 0><<<dim3(128, 1, 2), 256, 0, stream>>>(
      d1b, wd2p, d2b, b_dc2, 8000, 256, 1024, 1024, 100, 512, 0,
      2, 63, 262144LL, 0, 0);

  // --- final dot + sigmoid -> out (sc1 | sc2) fp32
  k_final<<<dim3(16000), 256, 0, stream>>>(d2b, ws + off_qv, b_mlp, out);
}

// Round 6
// 884.192 us; speedup vs baseline: 1.0637x; 1.0637x over previous
//
#include <hip/hip_runtime.h>
#include <hip/hip_bf16.h>
#include <math.h>

// Problem constants
#define BB 4
#define MM 20
#define LL 200
#define INC 2048
#define C1 512
#define C2 256
#define CDIM 300
#define DC1 512
#define DC2 256
#define SDIM 1024
#define BM 80           // B*M
#define L2 100          // L/2
#define L4 50           // L/4

typedef unsigned short u16;
typedef __attribute__((ext_vector_type(8))) short bf16x8;
typedef __attribute__((ext_vector_type(4))) float f32x4;

__device__ __forceinline__ u16 f2bf_rne(float f) {
  unsigned u = __float_as_uint(f);
  unsigned r = u + 0x7FFFu + ((u >> 16) & 1u);
  return (u16)(r >> 16);
}
__device__ __forceinline__ float bf2f(u16 v) {
  return __uint_as_float(((unsigned)v) << 16);
}

// async global -> LDS, 16 B per lane. LDS dest = wave-uniform base + lane*16.
__device__ __forceinline__ void gload16(const u16* g, u16* l) {
  __builtin_amdgcn_global_load_lds(
      (const __attribute__((address_space(1))) void*)g,
      (__attribute__((address_space(3))) void*)l, 16, 0, 0);
}

// ---------------- batch fp32 -> bf16 with 2-row zero padding: [80][204][2048] ----------------
__global__ void k_cast_pad_batch(const float* __restrict__ in, u16* __restrict__ out) {
  int idx = blockIdx.x * 256 + threadIdx.x;   // octet index
  if (idx >= 80 * 204 * 256) return;
  int c8 = idx % 256;
  int pi = (idx / 256) % 204;
  int n  = idx / (256 * 204);
  uint4 o = make_uint4(0u, 0u, 0u, 0u);
  if (pi >= 2 && pi < 202) {
    const float* p = in + ((long long)(n * 200 + pi - 2) * 2048 + c8 * 8);
    float4 a = *(const float4*)p;
    float4 b = *(const float4*)(p + 4);
    o.x = (unsigned)f2bf_rne(a.x) | ((unsigned)f2bf_rne(a.y) << 16);
    o.y = (unsigned)f2bf_rne(a.z) | ((unsigned)f2bf_rne(a.w) << 16);
    o.z = (unsigned)f2bf_rne(b.x) | ((unsigned)f2bf_rne(b.y) << 16);
    o.w = (unsigned)f2bf_rne(b.z) | ((unsigned)f2bf_rne(b.w) << 16);
  }
  *(uint4*)(out + (long long)idx * 8) = o;
}

// ---------------- zero the pad rows of a padded [n][rpad][cin] bf16 tensor ----------------
__global__ void k_zero_pad(u16* __restrict__ p, int ncnt, int rpad, int lr, int P,
                           int cin8, int total) {
  int idx = blockIdx.x * 256 + threadIdx.x;
  if (idx >= total) return;
  int c = idx % cin8;
  int pr = (idx / cin8) % (rpad - lr);
  int n = idx / (cin8 * (rpad - lr));
  int row = (pr < P) ? pr : lr + pr;
  *(uint4*)(p + ((long long)(n * rpad + row) * cin8 + c) * 8) = make_uint4(0, 0, 0, 0);
}

// ---------------- generic fp32 -> bf16 cast ----------------
__global__ void k_cast_bf16(const float* __restrict__ in, u16* __restrict__ out, int n8) {
  int idx = blockIdx.x * 256 + threadIdx.x;
  if (idx >= n8) return;
  const float4* p = (const float4*)in + (long long)idx * 2;
  float4 a = p[0], b = p[1];
  uint4 o;
  o.x = (unsigned)f2bf_rne(a.x) | ((unsigned)f2bf_rne(a.y) << 16);
  o.y = (unsigned)f2bf_rne(a.z) | ((unsigned)f2bf_rne(a.w) << 16);
  o.z = (unsigned)f2bf_rne(b.x) | ((unsigned)f2bf_rne(b.y) << 16);
  o.w = (unsigned)f2bf_rne(b.z) | ((unsigned)f2bf_rne(b.w) << 16);
  *(uint4*)(out + (long long)idx * 8) = o;
}

// conv weight [co][ci][t] -> [co][t][ci]  (= B[N][K], K = 5*Cin)
__global__ void k_conv_w_t(const float* __restrict__ in, u16* __restrict__ out,
                           int Cout, int Cin, int Kk) {
  int idx = blockIdx.x * 256 + threadIdx.x;
  int total = Cout * Cin * Kk;
  if (idx >= total) return;
  int ci = idx % Cin;
  int t  = (idx / Cin) % Kk;
  int co = idx / (Cin * Kk);
  out[idx] = f2bf_rne(in[(co * Cin + ci) * Kk + t]);
}

// deconv weight [ci][co][4] -> per-parity conv weights [z][co][tt][ci], t = 3 - z - 2*tt
__global__ void k_deconv_w_par(const float* __restrict__ in, u16* __restrict__ out,
                               int Cin, int Cout) {
  int idx = blockIdx.x * 256 + threadIdx.x;
  int total = Cin * Cout * 4;
  if (idx >= total) return;
  int ci = idx % Cin;
  int tt = (idx / Cin) & 1;
  int co = (idx / (2 * Cin)) % Cout;
  int zz = idx / (2 * Cin * Cout);
  out[idx] = f2bf_rne(in[(ci * Cout + co) * 4 + 3 - zz - 2 * tt]);
}

// ---------------- small precompute: q[z][b][c], v[z][b][c] ----------------
__global__ __launch_bounds__(256) void k_prep_small(
    const float* __restrict__ concept1, const float* __restrict__ concept2,
    const float* __restrict__ w_ca1, const float* __restrict__ w_sim1,
    const float* __restrict__ w_sim2, const float* __restrict__ w_mlp,
    float* __restrict__ qv) {
  int cz = blockIdx.x >> 2;
  int b  = blockIdx.x & 3;
  const float* con = cz ? concept2 : concept1;
  __shared__ float cvec[CDIM];
  __shared__ float chat[SDIM];
  int tid = threadIdx.x;
  for (int j = tid; j < CDIM; j += 256) cvec[j] = con[b * CDIM + j];
  __syncthreads();
  float accq = 0.f;
  for (int j = 0; j < CDIM; ++j) accq += cvec[j] * w_ca1[tid * CDIM + j];
  qv[(cz * 4 + b) * 256 + tid] = accq;
  for (int i = 0; i < 4; ++i) {
    int s = tid + i * 256;
    float a2 = 0.f;
    for (int j = 0; j < CDIM; ++j) a2 += cvec[j] * w_sim2[s * CDIM + j];
    chat[s] = a2 * w_mlp[s];
  }
  __syncthreads();
  float v = 0.f;
  for (int s = 0; s < SDIM; ++s) v += w_sim1[s * 256 + tid] * chat[s];
  qv[2048 + (cz * 4 + b) * 256 + tid] = v;
}

// ---------------- bf16-MFMA NT GEMM, fragment-order LDS + global_load_lds ----------------
// C = A * B^T, A row r -> (n=r/lr, l=r%lr), element k = tap*cin+ci reads padded
// A[(n*rpad + l + tap + off0)*cin + ci]; inputs pre-padded so NO bounds checks.
// LDS tiles stored in MFMA-fragment order: frag f = blk*2+ks (blk = 16-row group,
// ks = 32-k group) occupies 1 KB; lane ln's slot = f*1024 + ln*16 B, holding
// (row = blk*16 + (ln&15), k = ks*32 + (ln>>4)*8 .. +8). Since cin % 64 == 0 and
// chunks never straddle taps, each lane's global address is LINEAR in kc.
// EP_PLAIN: fp32 [M][N].  EP_POOL: maxpool2 over l + bias -> bf16 [n][orpad][N]
// at row ooff+ll.  EP_ILV: deconv parity z (pad = 1-z -> off0 = z, B += z*sB),
// bias -> bf16 at row n*orpad + ooff + 2*l + z.
#define EP_PLAIN 0
#define EP_POOL  1
#define EP_ILV   2

template <int EP>
__global__ __launch_bounds__(256) void k_gemm(
    const u16* __restrict__ A, const u16* __restrict__ Bw,
    void* __restrict__ Co, const float* __restrict__ bias,
    int M, int N, int Ktot, int nchunk,
    int lr, int rpad, int cin, int off0c,
    int gx, int gy, long long sB, int orpad, int ooff) {
  __shared__ __align__(16) u16 As[8192];
  __shared__ __align__(16) u16 Bs[8192];
  int id = blockIdx.x;
  int x = (id >> 3) % gx;
  int y = (id & 7) + 8 * ((id >> 3) / gx);
  if (y >= gy) return;
  int z = blockIdx.z;
  int off0 = (EP == EP_ILV) ? z : off0c;
  int row0 = y * 128, col0 = x * 128;
  int tid = threadIdx.x, w = tid >> 6, ln = tid & 63;
  const u16* Bz = Bw + (long long)z * sB;

  // per-lane DMA source pointers for this wave's 4 A-frags + 4 B-frags
  const u16* ga[4];
  const u16* gb[4];
  #pragma unroll
  for (int i = 0; i < 4; ++i) {
    int f = 4 * w + i, blk = f >> 1, ks = f & 1;
    int klocal = ks * 32 + (ln >> 4) * 8;
    int ar = row0 + blk * 16 + (ln & 15);
    int n_ = ar / lr, l_ = ar - n_ * lr;
    ga[i] = A + ((long long)(n_ * rpad + l_ + off0) * cin + klocal);
    int br = col0 + blk * 16 + (ln & 15);
    gb[i] = Bz + ((long long)br * Ktot + klocal);
  }
  u16* lA = As + 4 * w * 512;
  u16* lB = Bs + 4 * w * 512;

  f32x4 acc[4][4];
  #pragma unroll
  for (int i = 0; i < 4; ++i)
    #pragma unroll
    for (int j = 0; j < 4; ++j) acc[i][j] = (f32x4){0.f, 0.f, 0.f, 0.f};

  int wr2 = (w >> 1) * 4;   // A 16-row-block base for this wave
  int wc2 = (w & 1) * 4;    // B 16-col-block base

  for (int c = 0; c < nchunk; ++c) {
    #pragma unroll
    for (int i = 0; i < 4; ++i) {
      gload16(ga[i], lA + i * 512);
      gload16(gb[i], lB + i * 512);
      ga[i] += 64;
      gb[i] += 64;
    }
    __syncthreads();   // compiler inserts vmcnt(0) drain here
    #pragma unroll
    for (int ks = 0; ks < 2; ++ks) {
      bf16x8 af[4], bf[4];
      #pragma unroll
      for (int mi = 0; mi < 4; ++mi)
        af[mi] = *(const bf16x8*)&As[(((wr2 + mi) * 2 + ks) * 512) + ln * 8];
      #pragma unroll
      for (int ni = 0; ni < 4; ++ni)
        bf[ni] = *(const bf16x8*)&Bs[(((wc2 + ni) * 2 + ks) * 512) + ln * 8];
      #pragma unroll
      for (int mi = 0; mi < 4; ++mi)
        #pragma unroll
        for (int ni = 0; ni < 4; ++ni)
          acc[mi][ni] = __builtin_amdgcn_mfma_f32_16x16x32_bf16(
              af[mi], bf[ni], acc[mi][ni], 0, 0, 0);
    }
    __syncthreads();
  }

  // epilogue: C/D layout col = lane&15, row = (lane>>4)*4 + reg
  int c15 = ln & 15, q4 = (ln >> 4) * 4;
  int wrow = (w >> 1) * 64, wcol = (w & 1) * 64;
  if (EP == EP_PLAIN) {
    float* Cz = (float*)Co;
    #pragma unroll
    for (int mi = 0; mi < 4; ++mi) {
      int gbase = row0 + wrow + mi * 16 + q4;
      #pragma unroll
      for (int r = 0; r < 4; ++r) {
        int grow = gbase + r;
        if (grow < M) {
          #pragma unroll
          for (int ni = 0; ni < 4; ++ni) {
            int col = col0 + wcol + ni * 16 + c15;
            Cz[(long long)grow * N + col] = acc[mi][ni][r];
          }
        }
      }
    }
  } else if (EP == EP_POOL) {
    u16* Cz = (u16*)Co;
    int lrh = lr >> 1;
    #pragma unroll
    for (int mi = 0; mi < 4; ++mi) {
      int gbase = row0 + wrow + mi * 16 + q4;
      #pragma unroll
      for (int p = 0; p < 2; ++p) {
        int grow = gbase + 2 * p;
        if (grow < M) {
          int prow = grow >> 1;
          int n = prow / lrh, ll = prow - n * lrh;
          long long orow = (long long)n * orpad + ooff + ll;
          #pragma unroll
          for (int ni = 0; ni < 4; ++ni) {
            int col = col0 + wcol + ni * 16 + c15;
            float v = fmaxf(acc[mi][ni][2 * p], acc[mi][ni][2 * p + 1]) + bias[col];
            Cz[orow * N + col] = f2bf_rne(v);
          }
        }
      }
    }
  } else {  // EP_ILV
    u16* Cz = (u16*)Co;
    #pragma unroll
    for (int mi = 0; mi < 4; ++mi) {
      int gbase = row0 + wrow + mi * 16 + q4;
      #pragma unroll
      for (int r = 0; r < 4; ++r) {
        int grow = gbase + r;
        if (grow < M) {
          int n = grow / lr, l = grow - n * lr;
          long long orow = (long long)n * orpad + ooff + 2 * l + z;
          #pragma unroll
          for (int ni = 0; ni < 4; ++ni) {
            int col = col0 + wcol + ni * 16 + c15;
            Cz[orow * N + col] = f2bf_rne(acc[mi][ni][r] + bias[col]);
          }
        }
      }
    }
  }
}

// ---------------- attention: wave-parallel scores + softmax + weighted sum ----------------
__global__ __launch_bounds__(256) void k_attention(
    const float* __restrict__ kproj, const u16* __restrict__ t2b,
    const float* __restrict__ qv, const float* __restrict__ w_ca3,
    const int* __restrict__ seg_len, u16* __restrict__ rb) {
  int bm = blockIdx.x % BM;
  int cz = blockIdx.x / BM;
  int b = bm / MM;
  int tid = threadIdx.x, w = tid >> 6, ln = tid & 63;
  __shared__ float sq[256], sw[256], sa[L4 + 14];
  sq[tid] = qv[(cz * 4 + b) * 256 + tid];
  sw[tid] = w_ca3[tid];
  __syncthreads();
  int kmax = (seg_len[bm] + 3) >> 2;
  for (int k = w; k < L4; k += 4) {
    float val = 0.f;
    #pragma unroll
    for (int i = 0; i < 4; ++i) {
      int c = ln + 64 * i;
      val += tanhf(sq[c] + kproj[(bm * L4 + k) * 256 + c]) * sw[c];
    }
    for (int off = 32; off > 0; off >>= 1) val += __shfl_down(val, off, 64);
    if (ln == 0) sa[k] = (k < kmax) ? val : -1e15f;
  }
  __syncthreads();
  if (w == 0) {
    float sv = (ln < L4) ? sa[ln] : -3e38f;
    float mx = sv;
    for (int off = 32; off > 0; off >>= 1) mx = fmaxf(mx, __shfl_down(mx, off, 64));
    mx = __shfl(mx, 0, 64);
    float e = (ln < L4) ? expf(sv - mx) : 0.f;
    float s = e;
    for (int off = 32; off > 0; off >>= 1) s += __shfl_down(s, off, 64);
    s = __shfl(s, 0, 64);
    if (ln < L4) sa[ln] = e / s;
  }
  __syncthreads();
  float r = 0.f;
  for (int k = 0; k < L4; ++k) r += sa[k] * bf2f(t2b[(bm * L4 + k) * 256 + tid]);
  rb[(cz * BM + bm) * 256 + tid] = f2bf_rne(r);
}

// ---------------- build cat matrix, padded [80][52][768] bf16, interior rows 1..50 ----------------
__global__ void k_build_cat(const u16* __restrict__ t2b, const u16* __restrict__ rb,
                            u16* __restrict__ catm, int total) {
  int idx = blockIdx.x * 256 + threadIdx.x;
  if (idx >= total) return;
  int ci = idx % 768;
  int row = idx / 768;        // bm*50 + li
  int bm = row / L4, li = row - bm * L4;
  u16 v;
  if (ci < 256)      v = t2b[row * 256 + ci];
  else if (ci < 512) v = rb[bm * 256 + (ci - 256)];
  else               v = rb[(BM + bm) * 256 + (ci - 512)];
  catm[((long long)(bm * 52 + 1 + li)) * 768 + ci] = v;
}

// ---------------- final projection + sigmoid (reads bf16 d2) ----------------
__global__ __launch_bounds__(256) void k_final(
    const u16* __restrict__ d2b, const float* __restrict__ qv,
    const float* __restrict__ b_mlp, float* __restrict__ out) {
  int row = blockIdx.x;          // n*200 + lo
  int n = row / LL, lo = row % LL;
  int b = n / MM, m = n % MM;
  int tid = threadIdx.x;
  float v = bf2f(d2b[(long long)row * 256 + tid]);
  float p1 = v * qv[2048 + (0 * 4 + b) * 256 + tid];
  float p2 = v * qv[2048 + (1 * 4 + b) * 256 + tid];
  for (int off = 32; off > 0; off >>= 1) {
    p1 += __shfl_down(p1, off, 64);
    p2 += __shfl_down(p2, off, 64);
  }
  __shared__ float s1[4], s2[4];
  if ((tid & 63) == 0) { s1[tid >> 6] = p1; s2[tid >> 6] = p2; }
  __syncthreads();
  if (tid == 0) {
    float bmlp = b_mlp[0];
    float a1 = s1[0] + s1[1] + s1[2] + s1[3] + bmlp;
    float a2 = s2[0] + s2[1] + s2[2] + s2[3] + bmlp;
    int t_idx = m * LL + lo;
    out[b * 4000 + t_idx]         = 1.f / (1.f + expf(-a1));
    out[16000 + b * 4000 + t_idx] = 1.f / (1.f + expf(-a2));
  }
}

// ---------------- host ----------------
extern "C" void kernel_launch(void* const* d_in, const int* in_sizes, int n_in,
                              void* d_out, int out_size, void* d_ws, size_t ws_size,
                              hipStream_t stream) {
  const float* batch    = (const float*)d_in[0];
  const int*   seg_len  = (const int*)d_in[1];
  const float* concept1 = (const float*)d_in[2];
  const float* concept2 = (const float*)d_in[3];
  const float* w_conv1  = (const float*)d_in[4];
  const float* b_conv1  = (const float*)d_in[5];
  const float* w_conv2  = (const float*)d_in[6];
  const float* b_conv2  = (const float*)d_in[7];
  const float* w_ca1    = (const float*)d_in[8];
  const float* w_ca2    = (const float*)d_in[9];
  const float* w_ca3    = (const float*)d_in[10];
  const float* w_dc1    = (const float*)d_in[11];
  const float* b_dc1    = (const float*)d_in[12];
  const float* w_dc2    = (const float*)d_in[13];
  const float* b_dc2    = (const float*)d_in[14];
  const float* w_sim1   = (const float*)d_in[15];
  const float* w_sim2   = (const float*)d_in[16];
  const float* w_mlp    = (const float*)d_in[17];
  const float* b_mlp    = (const float*)d_in[18];
  float* out = (float*)d_out;

  float* ws = (float*)d_ws;
  // workspace (float units) — total 24,477,696 f = 97.9 MB
  const long long off_qv    = 0;          //      4,096
  const long long off_kproj = 4096;       //  1,024,000 fp32
  const long long off_rb    = 1028096;    //     20,480 (u16 40,960)
  const long long off_t1    = 1048576;    //  2,162,688 (t1b [80][104][512]+slack)
  const long long off_t2    = 3211264;    //    524,288 (t2b [4000][256]+slack)
  const long long off_w1b   = 3735552;    //  2,621,440
  const long long off_w2b   = 6356992;    //    327,680
  const long long off_wd1p  = 6684672;    //    786,432
  const long long off_wd2p  = 7471104;    //    262,144
  const long long off_wca2b = 7733248;    //     32,768
  const long long off_BIG   = 7766016;    // 16,711,680 (batchb -> catm/d1b/d2b)

  u16* rb    = (u16*)(ws + off_rb);
  u16* t1b   = (u16*)(ws + off_t1);
  u16* t2b   = (u16*)(ws + off_t2);
  u16* w1b   = (u16*)(ws + off_w1b);
  u16* w2b   = (u16*)(ws + off_w2b);
  u16* wd1p  = (u16*)(ws + off_wd1p);
  u16* wd2p  = (u16*)(ws + off_wd2p);
  u16* wca2b = (u16*)(ws + off_wca2b);
  u16* batchb = (u16*)(ws + off_BIG);               // [80][204][2048]
  u16* catm   = (u16*)(ws + off_BIG);               // [80][52][768]+slack (after conv1)
  u16* d1b    = (u16*)(ws + off_BIG) + 3342336;     // [80][102][512]+slack
  u16* d2b    = (u16*)(ws + off_BIG) + 7667712;     // [16000][256]

  // --- prep: padded bf16 batch, bf16 weights, small vectors ---
  k_cast_pad_batch<<<dim3(16320), 256, 0, stream>>>(batch, batchb);
  k_conv_w_t<<<dim3(20480), 256, 0, stream>>>(w_conv1, w1b, C1, INC, 5);
  k_conv_w_t<<<dim3(2560), 256, 0, stream>>>(w_conv2, w2b, C2, C1, 5);
  k_deconv_w_par<<<dim3(6144), 256, 0, stream>>>(w_dc1, wd1p, 3 * C2, DC1);
  k_deconv_w_par<<<dim3(2048), 256, 0, stream>>>(w_dc2, wd2p, DC1, DC2);
  k_cast_bf16<<<dim3(32), 256, 0, stream>>>(w_ca2, wca2b, 8192);
  k_prep_small<<<dim3(8), 256, 0, stream>>>(concept1, concept2, w_ca1, w_sim1, w_sim2,
                                            w_mlp, ws + off_qv);
  k_zero_pad<<<dim3(80), 256, 0, stream>>>(t1b, 80, 104, 100, 2, 64, 20480);

  // --- conv1 + pool + bias -> t1b [80][104][512] (M=16000,N=512,K=10240)
  k_gemm<EP_POOL><<<dim3(512), 256, 0, stream>>>(
      batchb, w1b, t1b, b_conv1, 16000, 512, 10240, 160,
      200, 204, 2048, 0, 4, 125, 0, 104, 2);

  // batchb dead -> zero pads of catm / d1b (they overlay it)
  k_zero_pad<<<dim3(60), 256, 0, stream>>>(catm, 80, 52, 50, 1, 96, 15360);
  k_zero_pad<<<dim3(40), 256, 0, stream>>>(d1b, 80, 102, 100, 1, 64, 10240);

  // --- conv2 + pool + bias -> t2b [4000][256] (M=8000,N=256,K=2560)
  k_gemm<EP_POOL><<<dim3(128), 256, 0, stream>>>(
      t1b, w2b, t2b, b_conv2, 8000, 256, 2560, 40,
      100, 104, 512, 0, 2, 63, 0, 50, 0);

  // --- kproj = t2 @ w_ca2^T -> fp32 [4000][256] (M=4000,N=256,K=256)
  k_gemm<EP_PLAIN><<<dim3(64), 256, 0, stream>>>(
      t2b, wca2b, ws + off_kproj, nullptr, 4000, 256, 256, 4,
      4000, 4000, 256, 0, 2, 32, 0, 0, 0);

  // --- attention -> rb bf16 [2][80][256]
  k_attention<<<dim3(160), 256, 0, stream>>>(ws + off_kproj, t2b, ws + off_qv,
                                             w_ca3, seg_len, rb);

  // --- cat -> catm padded [80][52][768]
  k_build_cat<<<dim3(12000), 256, 0, stream>>>(t2b, rb, catm, 4000 * 768);

  // --- deconv1: 2 parity convs + bias -> d1b [80][102][512] (M=4000,N=512,K=1536)
  k_gemm<EP_ILV><<<dim3(128, 1, 2), 256, 0, stream>>>(
      catm, wd1p, d1b, b_dc1, 4000, 512, 1536, 24,
      50, 52, 768, 0, 4, 32, 786432LL, 102, 1);

  // --- deconv2: 2 parity convs + bias -> d2b [16000][256] (M=8000,N=256,K=1024)
  k_gemm<EP_ILV><<<dim3(128, 1, 2), 256, 0, stream>>>(
      d1b, wd2p, d2b, b_dc2, 8000, 256, 1024, 16,
      100, 102, 512, 0, 2, 63, 262144LL, 200, 0);

  // --- final dot + sigmoid -> out (sc1 | sc2) fp32
  k_final<<<dim3(16000), 256, 0, stream>>>(d2b, ws + off_qv, b_mlp, out);
}